// Round 16
// baseline (182.292 us; speedup 1.0000x reference)
//
#include <hip/hip_runtime.h>
#include <math.h>

#define NROW 8192
#define DDIM 256
#define BM 128
#define BN 128
#define NT_SYM 2080     // 64*65/2 lower-triangular 128x128 tiles
#define NT_FULL 4096
#define NT_TOTAL (2 * NT_SYM + NT_FULL)   // 8256 tiles
#define NBLK 512        // persistent: exactly 2 blocks/CU, zero WG churn
#define NBIG 64         // first 64 blocks take 17 tiles, rest 16 (64*17+448*16=8256)

typedef __attribute__((ext_vector_type(16))) float f32x16;
typedef __attribute__((ext_vector_type(4)))  int   i32x4;
typedef __attribute__((ext_vector_type(8)))  int   i32x8;
typedef __attribute__((address_space(3))) unsigned int lds_u32;
typedef const __attribute__((address_space(1))) unsigned int glb_u32;

// DPP row_ror butterfly add: after ror 1,2,4,8 every lane of each 16-lane row
// holds the row sum. VALU pipe only — no DS traffic.
template <int CTRL>
static __device__ inline float dpp_ror_add(float v) {
    int s = __float_as_int(v);
    int r = __builtin_amdgcn_update_dpp(0, s, CTRL, 0xF, 0xF, true);
    return v + __int_as_float(r);
}
static __device__ inline float row16_sum(float v) {
    v = dpp_ror_add<0x121>(v);
    v = dpp_ror_add<0x122>(v);
    v = dpp_ror_add<0x124>(v);
    v = dpp_ror_add<0x128>(v);
    return v;
}

// Pack 4 floats -> 4 fp8 e4m3 bytes (HW cvt, OCP on gfx950 — self-consistent
// with the fp8 MFMA's decode).
static __device__ inline unsigned int pack_fp8x4(float a, float b, float c, float d) {
    int p = __builtin_amdgcn_cvt_pk_fp8_f32(a, b, 0, false);
    p = __builtin_amdgcn_cvt_pk_fp8_f32(c, d, p, true);
    return (unsigned int)p;
}

// One wave per row: L2-normalize H1/H2 rows, scale by sqrt(2*log2(e)) so the
// fp8 Gram entries come out as 2*log2(e)*s -> exp(2s) == exp2(acc).
// diag[row] = 2*dot(z1n,z2n) fp32 (exact). Zero-inits rowsums and out.
__global__ __launch_bounds__(256) void normalize_kernel(
        const float* __restrict__ h1, const float* __restrict__ h2,
        unsigned char* __restrict__ z1b, unsigned char* __restrict__ z2b,
        float* __restrict__ diag,
        float* __restrict__ rs1, float* __restrict__ rs2,
        float* __restrict__ rbr, float* __restrict__ rbc,
        float* __restrict__ out) {
    int wave = threadIdx.x >> 6;
    int lane = threadIdx.x & 63;
    int row  = blockIdx.x * 4 + wave;
    if (blockIdx.x == 0 && threadIdx.x == 0) out[0] = 0.f;
    const float4* p1 = (const float4*)(h1 + (size_t)row * DDIM);
    const float4* p2 = (const float4*)(h2 + (size_t)row * DDIM);
    float4 a = p1[lane];
    float4 b = p2[lane];
    float s1 = a.x*a.x + a.y*a.y + a.z*a.z + a.w*a.w;
    float s2 = b.x*b.x + b.y*b.y + b.z*b.z + b.w*b.w;
    #pragma unroll
    for (int m = 1; m < 64; m <<= 1) { s1 += __shfl_xor(s1, m); s2 += __shfl_xor(s2, m); }
    float r1 = 1.0f / fmaxf(sqrtf(s1), 1e-12f);
    float r2 = 1.0f / fmaxf(sqrtf(s2), 1e-12f);
    float n1x = a.x*r1, n1y = a.y*r1, n1z = a.z*r1, n1w = a.w*r1;
    float n2x = b.x*r2, n2y = b.y*r2, n2z = b.z*r2, n2w = b.w*r2;
    float dt = n1x*n2x + n1y*n2y + n1z*n2z + n1w*n2w;
    #pragma unroll
    for (int m = 1; m < 64; m <<= 1) dt += __shfl_xor(dt, m);
    if (lane == 0) {
        diag[row] = 2.0f * dt;
        rs1[row] = 0.f; rs2[row] = 0.f; rbr[row] = 0.f; rbc[row] = 0.f;
    }
    const float SC = 1.69864364f;   // sqrt(2 * log2(e))
    ((unsigned int*)(z1b + (size_t)row * DDIM))[lane] =
        pack_fp8x4(n1x*SC, n1y*SC, n1z*SC, n1w*SC);
    ((unsigned int*)(z2b + (size_t)row * DDIM))[lane] =
        pack_fp8x4(n2x*SC, n2y*SC, n2z*SC, n2w*SC);
}

struct Tile {
    const unsigned char* Ap;
    const unsigned char* Bp;
    float* rowsum;
    float* colsum;
    int rt, ct;
};

static __device__ inline Tile decode_tile(int t,
        const unsigned char* z1, const unsigned char* z2,
        float* rs1, float* rs2, float* rbr, float* rbc) {
    Tile ti;
    int kind, tt;
    if (t < NT_SYM)          { kind = 0; tt = t; }
    else if (t < 2 * NT_SYM) { kind = 1; tt = t - NT_SYM; }
    else                     { kind = 2; tt = t - 2 * NT_SYM; }
    int by, bx;
    if (kind == 2) {
        by = tt >> 6; bx = tt & 63;
        ti.Ap = z1; ti.Bp = z2; ti.rowsum = rbr; ti.colsum = rbc;
    } else {
        by = (int)((sqrtf(8.0f * (float)tt + 1.0f) - 1.0f) * 0.5f);
        while ((by + 1) * (by + 2) / 2 <= tt) ++by;
        while (by * (by + 1) / 2 > tt) --by;
        bx = tt - by * (by + 1) / 2;          // bx <= by
        const unsigned char* z = (kind == 0) ? z1 : z2;
        ti.Ap = z; ti.Bp = z;
        ti.rowsum = (kind == 0) ? rs1 : rs2;
        ti.colsum = (bx == by) ? nullptr : ti.rowsum;
    }
    ti.rt = by * BM; ti.ct = bx * BN;
    return ti;
}

// R18: persistent blocks + cross-tile double-buffered A. Evidence: the 81us
// floor survived +/-30% changes in VALU, DS, occupancy (40<->73%), barriers
// — per-block wall ~18K cyc, of which summed pipe work explains <40%. The
// shared feature of all variants: 8256 short dispatches each paying an
// unhidden stage-drain + WG launch/drain ramp. Fix: 512 blocks (exactly
// 2/CU), each runs 16-17 tiles; A for tile t+1 is staged into the OTHER
// 32KB buffer right after tile t's k-loop, so its latency hides under the
// ~800cy epilogue; the barrier then drains an almost-complete transfer.
// LDS 2x32K + 6K scratch = 70KB (legal on gfx950; m201 example uses 128KB).
__global__ __launch_bounds__(512, 4) void expsum_kernel(
        const unsigned char* __restrict__ z1, const unsigned char* __restrict__ z2,
        float* __restrict__ rs1, float* __restrict__ rs2,
        float* __restrict__ rbr, float* __restrict__ rbc) {
    int bid = blockIdx.x;
    int start, cnt;
    if (bid < NBIG) { start = bid * 17;                     cnt = 17; }
    else            { start = NBIG * 17 + (bid - NBIG) * 16; cnt = 16; }

    __shared__ __align__(16) unsigned char lA[2][BM * DDIM];  // 64 KB dbuf A
    __shared__ float lds_rp[4][2][BM];                        // [wc4][sub16][row] 4 KB
    __shared__ float lds_cp[2][2][BN];                        // [wr][kh][col]     2 KB

    const int tid  = threadIdx.x;
    const int lane = tid & 63;
    const int wid  = tid >> 6;           // 0..7
    const int wr   = wid & 1;            // 64-row half
    const int wc4  = wid >> 1;           // 32-col quarter (0..3)
    const int l31  = lane & 31;
    const int kh   = lane >> 5;          // k-half of the 64-wide k-step

    // DMA lane mapping: 16 lanes per 256-B row, 4 rows per wave-instruction.
    const int srow = lane >> 4;          // row within 4-row group
    const int sgt  = lane & 15;          // physical 16B granule (= DMA slot)
    const int key  = lane & 15;          // read-side swizzle key (= row&15)

    const int aoff0 = (wr * 64 + l31) * DDIM;        // rows 0..31 of wave tile
    const int aoff1 = aoff0 + 32 * DDIM;             // rows 32..63

    // Prologue: decode + stage tile 'start' into buffer 0.
    Tile cur_t = decode_tile(start, z1, z2, rs1, rs2, rbr, rbc);
    {
        #pragma unroll
        for (int p = 0; p < 4; ++p) {
            int r0 = (p * 8 + wid) * 4;
            int r  = r0 + srow;
            int gg = sgt ^ (r & 15);
            const unsigned char* ga = cur_t.Ap + (size_t)(cur_t.rt + r) * DDIM + gg * 16;
            __builtin_amdgcn_global_load_lds((glb_u32*)ga,
                (lds_u32*)(lA[0] + r0 * DDIM), 16, 0, 0);
        }
    }
    int cur = 0;

    for (int i = 0; i < cnt; ++i) {
        // Top barrier: buf[cur] staged (drained at previous iteration's
        // second barrier, or prologue drain here for i==0); also protects
        // scratch reuse (all waves past previous combine).
        __syncthreads();

        // B gathers + k-loop on buf[cur] — no barriers inside.
        const unsigned char* gB =
            cur_t.Bp + (size_t)(cur_t.ct + wc4 * 32 + l31) * DDIM + kh * 32;
        const unsigned char* bufA = lA[cur];

        f32x16 acc0, acc1;
        #pragma unroll
        for (int r = 0; r < 16; ++r) { acc0[r] = 0.f; acc1[r] = 0.f; }

        #pragma unroll
        for (int kt = 0; kt < 2; ++kt) {
            #pragma unroll
            for (int ks = 0; ks < 2; ++ks) {     // 4 x K=64
                const int g0   = kt * 8 + ks * 4 + kh * 2;  // even granule
                const int off0 = (g0 ^ key) * 16;
                const int off1 = off0 ^ 16;
                const int bo   = kt * 128 + ks * 64;
                i32x8 a0, a1, bv;
                *((i32x4*)&a0)     = *(const i32x4*)(bufA + aoff0 + off0);
                *((i32x4*)&a0 + 1) = *(const i32x4*)(bufA + aoff0 + off1);
                *((i32x4*)&a1)     = *(const i32x4*)(bufA + aoff1 + off0);
                *((i32x4*)&a1 + 1) = *(const i32x4*)(bufA + aoff1 + off1);
                *((i32x4*)&bv)     = *(const i32x4*)(gB + bo);
                *((i32x4*)&bv + 1) = *(const i32x4*)(gB + bo + 16);
                acc0 = __builtin_amdgcn_mfma_scale_f32_32x32x64_f8f6f4(
                    a0, bv, acc0, 0, 0, 0, 0x7F7F7F7F, 0, 0x7F7F7F7F);
                acc1 = __builtin_amdgcn_mfma_scale_f32_32x32x64_f8f6f4(
                    a1, bv, acc1, 0, 0, 0, 0x7F7F7F7F, 0, 0x7F7F7F7F);
            }
        }

        // Issue next tile's A stage into the OTHER buffer. Safe: all waves'
        // reads of buf[cur^1] finished before this iteration's top barrier.
        // Latency hides under the epilogue below; the next barrier drains it.
        Tile next_t = cur_t;
        if (i + 1 < cnt) {
            next_t = decode_tile(start + i + 1, z1, z2, rs1, rs2, rbr, rbc);
            #pragma unroll
            for (int p = 0; p < 4; ++p) {
                int r0 = (p * 8 + wid) * 4;
                int r  = r0 + srow;
                int gg = sgt ^ (r & 15);
                const unsigned char* ga =
                    next_t.Ap + (size_t)(next_t.rt + r) * DDIM + gg * 16;
                __builtin_amdgcn_global_load_lds((glb_u32*)ga,
                    (lds_u32*)(lA[cur ^ 1] + r0 * DDIM), 16, 0, 0);
            }
        }

        // Epilogue: C/D layout (32x32): col = lane&31,
        // row = (reg&3)+8*(reg>>2)+4*kh. acc = 2*log2e*s -> raw v_exp_f32.
        // Writers (lanes 0/16/32/48) store plain; every scratch slot written
        // exactly once per tile across the 8 waves.
        float cp = 0.f;
        #pragma unroll
        for (int r = 0; r < 16; ++r) {
            float e0 = __builtin_amdgcn_exp2f(acc0[r]);
            float e1 = __builtin_amdgcn_exp2f(acc1[r]);
            cp += e0 + e1;
            float v0 = row16_sum(e0);
            float v1 = row16_sum(e1);
            if ((lane & 15) == 0) {           // lanes 0,16,32,48
                int rloc = wr * 64 + 4 * kh + (r & 3) + 8 * (r >> 2);
                int sub16 = l31 >> 4;
                lds_rp[wc4][sub16][rloc]      = v0;
                lds_rp[wc4][sub16][rloc + 32] = v1;
            }
        }
        lds_cp[wr][kh][wc4 * 32 + l31] = cp;
        __syncthreads();   // scratch complete; drains the (mostly done) stage

        // Combine: one atomic per row / col of this 128x128 tile.
        if (tid < BM) {
            float s = lds_rp[0][0][tid] + lds_rp[0][1][tid]
                    + lds_rp[1][0][tid] + lds_rp[1][1][tid]
                    + lds_rp[2][0][tid] + lds_rp[2][1][tid]
                    + lds_rp[3][0][tid] + lds_rp[3][1][tid];
            atomicAdd(&cur_t.rowsum[cur_t.rt + tid], s);
        } else if (cur_t.colsum && tid < 2 * BM) {
            int c = tid - BM;                // 0..127
            float s = lds_cp[0][0][c] + lds_cp[0][1][c]
                    + lds_cp[1][0][c] + lds_cp[1][1][c];
            atomicAdd(&cur_t.colsum[cur_t.ct + c], s);
        }

        cur_t = next_t;
        cur ^= 1;
    }
}

// 32 blocks x 256 threads, one row each; block-reduce then one atomicAdd.
__global__ __launch_bounds__(256) void finalize_kernel(
        const float* __restrict__ rs1, const float* __restrict__ rs2,
        const float* __restrict__ rbr, const float* __restrict__ rbc,
        const float* __restrict__ diag, float* __restrict__ out) {
    __shared__ float s4[4];
    const float E2 = 7.38905609893065f;   // exp(1/tau), tau=0.5
    int i = blockIdx.x * 256 + threadIdx.x;
    float den1 = rs1[i] + rbr[i] - E2;
    float den2 = rs2[i] + rbc[i] - E2;
    float v = 0.5f * (logf(den1) + logf(den2)) - diag[i];
    #pragma unroll
    for (int m = 1; m < 64; m <<= 1) v += __shfl_xor(v, m);
    if ((threadIdx.x & 63) == 0) s4[threadIdx.x >> 6] = v;
    __syncthreads();
    if (threadIdx.x == 0) {
        float t = (s4[0] + s4[1] + s4[2] + s4[3]) * (1.0f / (float)NROW);
        atomicAdd(out, t);
    }
}

extern "C" void kernel_launch(void* const* d_in, const int* in_sizes, int n_in,
                              void* d_out, int out_size, void* d_ws, size_t ws_size,
                              hipStream_t stream) {
    const float* h1 = (const float*)d_in[0];
    const float* h2 = (const float*)d_in[1];
    float* out = (float*)d_out;

    char* ws = (char*)d_ws;
    unsigned char* z1b = (unsigned char*)ws;                             // 2 MB
    unsigned char* z2b = (unsigned char*)(ws + (size_t)NROW * DDIM);     // 2 MB
    float* sums = (float*)(ws + (size_t)2 * NROW * DDIM);
    float* rs1  = sums;
    float* rs2  = sums + NROW;
    float* rbr  = sums + 2 * NROW;
    float* rbc  = sums + 3 * NROW;
    float* diag = sums + 4 * NROW;

    normalize_kernel<<<NROW / 4, 256, 0, stream>>>(h1, h2, z1b, z2b, diag,
                                                   rs1, rs2, rbr, rbc, out);

    expsum_kernel<<<NBLK, 512, 0, stream>>>(z1b, z2b, rs1, rs2, rbr, rbc);

    finalize_kernel<<<NROW / 256, 256, 0, stream>>>(rs1, rs2, rbr, rbc, diag, out);
}

// Round 17
// 139.123 us; speedup vs baseline: 1.3103x; 1.3103x over previous
//
#include <hip/hip_runtime.h>
#include <math.h>

#define NROW 8192
#define DDIM 256
#define BM 128
#define BN 128          // full tile per block; 8 waves of 64x32 sub-tiles
#define NT_SYM 2080     // 64*65/2 lower-triangular 128x128 tiles
#define NT_FULL 4096
#define NT_TOTAL (2 * NT_SYM + NT_FULL)   // 8256 tiles = grid

typedef __attribute__((ext_vector_type(16))) float f32x16;
typedef __attribute__((ext_vector_type(4)))  int   i32x4;
typedef __attribute__((ext_vector_type(8)))  int   i32x8;
typedef __attribute__((address_space(3))) unsigned int lds_u32;
typedef const __attribute__((address_space(1))) unsigned int glb_u32;

// DPP row_ror butterfly add: after ror 1,2,4,8 every lane of each 16-lane row
// holds the row sum. VALU pipe only — no DS traffic.
template <int CTRL>
static __device__ inline float dpp_ror_add(float v) {
    int s = __float_as_int(v);
    int r = __builtin_amdgcn_update_dpp(0, s, CTRL, 0xF, 0xF, true);
    return v + __int_as_float(r);
}
static __device__ inline float row16_sum(float v) {
    v = dpp_ror_add<0x121>(v);
    v = dpp_ror_add<0x122>(v);
    v = dpp_ror_add<0x124>(v);
    v = dpp_ror_add<0x128>(v);
    return v;
}

// Pack 4 floats -> 4 fp8 e4m3 bytes (HW cvt, OCP on gfx950 — self-consistent
// with the fp8 MFMA's decode).
static __device__ inline unsigned int pack_fp8x4(float a, float b, float c, float d) {
    int p = __builtin_amdgcn_cvt_pk_fp8_f32(a, b, 0, false);
    p = __builtin_amdgcn_cvt_pk_fp8_f32(c, d, p, true);
    return (unsigned int)p;
}

// One wave per row: L2-normalize H1/H2 rows, scale by sqrt(2*log2(e)) so the
// fp8 Gram entries come out as 2*log2(e)*s -> exp(2s) == exp2(acc).
// diag[row] = 2*dot(z1n,z2n) fp32 (exact). Zero-inits rowsums and out.
__global__ __launch_bounds__(256) void normalize_kernel(
        const float* __restrict__ h1, const float* __restrict__ h2,
        unsigned char* __restrict__ z1b, unsigned char* __restrict__ z2b,
        float* __restrict__ diag,
        float* __restrict__ rs1, float* __restrict__ rs2,
        float* __restrict__ rbr, float* __restrict__ rbc,
        float* __restrict__ out) {
    int wave = threadIdx.x >> 6;
    int lane = threadIdx.x & 63;
    int row  = blockIdx.x * 4 + wave;
    if (blockIdx.x == 0 && threadIdx.x == 0) out[0] = 0.f;
    const float4* p1 = (const float4*)(h1 + (size_t)row * DDIM);
    const float4* p2 = (const float4*)(h2 + (size_t)row * DDIM);
    float4 a = p1[lane];
    float4 b = p2[lane];
    float s1 = a.x*a.x + a.y*a.y + a.z*a.z + a.w*a.w;
    float s2 = b.x*b.x + b.y*b.y + b.z*b.z + b.w*b.w;
    #pragma unroll
    for (int m = 1; m < 64; m <<= 1) { s1 += __shfl_xor(s1, m); s2 += __shfl_xor(s2, m); }
    float r1 = 1.0f / fmaxf(sqrtf(s1), 1e-12f);
    float r2 = 1.0f / fmaxf(sqrtf(s2), 1e-12f);
    float n1x = a.x*r1, n1y = a.y*r1, n1z = a.z*r1, n1w = a.w*r1;
    float n2x = b.x*r2, n2y = b.y*r2, n2z = b.z*r2, n2w = b.w*r2;
    float dt = n1x*n2x + n1y*n2y + n1z*n2z + n1w*n2w;
    #pragma unroll
    for (int m = 1; m < 64; m <<= 1) dt += __shfl_xor(dt, m);
    if (lane == 0) {
        diag[row] = 2.0f * dt;
        rs1[row] = 0.f; rs2[row] = 0.f; rbr[row] = 0.f; rbc[row] = 0.f;
    }
    const float SC = 1.69864364f;   // sqrt(2 * log2(e))
    ((unsigned int*)(z1b + (size_t)row * DDIM))[lane] =
        pack_fp8x4(n1x*SC, n1y*SC, n1z*SC, n1w*SC);
    ((unsigned int*)(z2b + (size_t)row * DDIM))[lane] =
        pack_fp8x4(n2x*SC, n2y*SC, n2z*SC, n2w*SC);
}

// R19 = R17 frozen (best: 137.9 us total, expsum 81.1-81.4 us).
// R18's persistent-block probe regressed (FETCH 2x: lost cross-block
// temporal L2 sharing; occupancy 73->38%). Final structure: 8 waves of
// 64x32 sub-tiles per 128x128 tile; A staged once via global_load_lds
// with 4-bit granule swizzle; B direct per-lane gathers; scaled fp8
// 32x32x64 MFMA (4.7 PF path); no main-loop barriers; DPP row-sums;
// plain-write scratch; 256 atomics/tile.
__global__ __launch_bounds__(512, 6) void expsum_kernel(
        const unsigned char* __restrict__ z1, const unsigned char* __restrict__ z2,
        float* __restrict__ rs1, float* __restrict__ rs2,
        float* __restrict__ rbr, float* __restrict__ rbc) {
    int t = blockIdx.x;
    int kind, tt;
    if (t < NT_SYM)            { kind = 0; tt = t; }
    else if (t < 2 * NT_SYM)   { kind = 1; tt = t - NT_SYM; }
    else                       { kind = 2; tt = t - 2 * NT_SYM; }

    int by, bx;
    const unsigned char *Ap, *Bp;
    float *rowsum, *colsum;
    if (kind == 2) {
        by = tt >> 6; bx = tt & 63;
        Ap = z1; Bp = z2; rowsum = rbr; colsum = rbc;
    } else {
        by = (int)((sqrtf(8.0f * (float)tt + 1.0f) - 1.0f) * 0.5f);
        while ((by + 1) * (by + 2) / 2 <= tt) ++by;
        while (by * (by + 1) / 2 > tt) --by;
        bx = tt - by * (by + 1) / 2;          // bx <= by
        const unsigned char* z = (kind == 0) ? z1 : z2;
        Ap = z; Bp = z;
        rowsum = (kind == 0) ? rs1 : rs2;
        colsum = (bx == by) ? nullptr : rowsum;
    }

    const int rt = by * BM;
    const int ct = bx * BN;

    __shared__ __align__(16) unsigned char lA[BM * DDIM];  // 32 KB full-K A
    __shared__ float lds_rp[4][2][BM];                     // [wc4][sub16][row] 4 KB
    __shared__ float lds_cp[2][2][BN];                     // [wr][kh][col]     2 KB

    const int tid  = threadIdx.x;
    const int lane = tid & 63;
    const int wid  = tid >> 6;           // 0..7
    const int wr   = wid & 1;            // 64-row half
    const int wc4  = wid >> 1;           // 32-col quarter (0..3)
    const int l31  = lane & 31;
    const int kh   = lane >> 5;          // k-half of the 64-wide k-step

    // DMA lane mapping: 16 lanes per 256-B row, 4 rows per wave-instruction.
    const int srow = lane >> 4;          // row within 4-row group
    const int sgt  = lane & 15;          // physical 16B granule (= DMA slot)

    const int key  = lane & 15;          // read-side swizzle key (= row&15)

    const int aoff0 = (wr * 64 + l31) * DDIM;        // rows 0..31 of wave tile
    const int aoff1 = aoff0 + 32 * DDIM;             // rows 32..63

    // Stage full 128x256B A: 32 wave-DMAs, 4 per wave, 16 B/lane, linear
    // dest, swizzled source granule gg = sgt ^ (r&15).
    #pragma unroll
    for (int p = 0; p < 4; ++p) {
        int r0 = (p * 8 + wid) * 4;
        int r  = r0 + srow;
        int gg = sgt ^ (r & 15);
        const unsigned char* ga = Ap + (size_t)(rt + r) * DDIM + gg * 16;
        __builtin_amdgcn_global_load_lds((glb_u32*)ga, (lds_u32*)(lA + r0 * DDIM), 16, 0, 0);
    }
    __syncthreads();                     // A staged

    // B base: this wave's 32 cols, per-lane row ct + wc4*32 + l31.
    const unsigned char* gB = Bp + (size_t)(ct + wc4 * 32 + l31) * DDIM + kh * 32;

    f32x16 acc0, acc1;                   // rows mi=0 / mi=1 of the 64-row half
    #pragma unroll
    for (int r = 0; r < 16; ++r) { acc0[r] = 0.f; acc1[r] = 0.f; }

    #pragma unroll
    for (int kt = 0; kt < 2; ++kt) {
        #pragma unroll
        for (int ks = 0; ks < 2; ++ks) {     // 4 x K=64, no barriers
            const int g0   = kt * 8 + ks * 4 + kh * 2;  // even granule
            const int off0 = (g0 ^ key) * 16;
            const int off1 = off0 ^ 16;
            const int bo   = kt * 128 + ks * 64;
            i32x8 a0, a1, bv;
            *((i32x4*)&a0)     = *(const i32x4*)(lA + aoff0 + off0);
            *((i32x4*)&a0 + 1) = *(const i32x4*)(lA + aoff0 + off1);
            *((i32x4*)&a1)     = *(const i32x4*)(lA + aoff1 + off0);
            *((i32x4*)&a1 + 1) = *(const i32x4*)(lA + aoff1 + off1);
            *((i32x4*)&bv)     = *(const i32x4*)(gB + bo);
            *((i32x4*)&bv + 1) = *(const i32x4*)(gB + bo + 16);
            acc0 = __builtin_amdgcn_mfma_scale_f32_32x32x64_f8f6f4(
                a0, bv, acc0, 0, 0, 0, 0x7F7F7F7F, 0, 0x7F7F7F7F);
            acc1 = __builtin_amdgcn_mfma_scale_f32_32x32x64_f8f6f4(
                a1, bv, acc1, 0, 0, 0, 0x7F7F7F7F, 0, 0x7F7F7F7F);
        }
    }

    // C/D layout (32x32): col = lane&31, row = (reg&3)+8*(reg>>2)+4*kh.
    // acc = 2*log2e*s -> raw v_exp_f32 (inputs bounded ~|2.9|).
    // Writers (lanes 0/16/32/48) store plain — every scratch slot exactly
    // once across the 8 waves (1024 slots = 8 waves x 128 writes).
    float cp = 0.f;
    #pragma unroll
    for (int r = 0; r < 16; ++r) {
        float e0 = __builtin_amdgcn_exp2f(acc0[r]);
        float e1 = __builtin_amdgcn_exp2f(acc1[r]);
        cp += e0 + e1;                    // same col, rows of both mi blocks
        float v0 = row16_sum(e0);
        float v1 = row16_sum(e1);
        if ((lane & 15) == 0) {           // lanes 0,16,32,48
            int rloc = wr * 64 + 4 * kh + (r & 3) + 8 * (r >> 2);
            int sub16 = l31 >> 4;         // 16-col group within the 32 cols
            lds_rp[wc4][sub16][rloc]      = v0;
            lds_rp[wc4][sub16][rloc + 32] = v1;
        }
    }
    lds_cp[wr][kh][wc4 * 32 + l31] = cp;
    __syncthreads();

    // Final combine: one atomic per row and per col of the 128x128 tile.
    if (tid < BM) {
        float s = lds_rp[0][0][tid] + lds_rp[0][1][tid]
                + lds_rp[1][0][tid] + lds_rp[1][1][tid]
                + lds_rp[2][0][tid] + lds_rp[2][1][tid]
                + lds_rp[3][0][tid] + lds_rp[3][1][tid];
        atomicAdd(&rowsum[rt + tid], s);
    } else if (colsum && tid < 2 * BM) {
        int c = tid - BM;                // 0..127
        float s = lds_cp[0][0][c] + lds_cp[0][1][c]
                + lds_cp[1][0][c] + lds_cp[1][1][c];
        atomicAdd(&colsum[ct + c], s);
    }
}

// 32 blocks x 256 threads, one row each; block-reduce then one atomicAdd.
__global__ __launch_bounds__(256) void finalize_kernel(
        const float* __restrict__ rs1, const float* __restrict__ rs2,
        const float* __restrict__ rbr, const float* __restrict__ rbc,
        const float* __restrict__ diag, float* __restrict__ out) {
    __shared__ float s4[4];
    const float E2 = 7.38905609893065f;   // exp(1/tau), tau=0.5
    int i = blockIdx.x * 256 + threadIdx.x;
    float den1 = rs1[i] + rbr[i] - E2;
    float den2 = rs2[i] + rbc[i] - E2;
    float v = 0.5f * (logf(den1) + logf(den2)) - diag[i];
    #pragma unroll
    for (int m = 1; m < 64; m <<= 1) v += __shfl_xor(v, m);
    if ((threadIdx.x & 63) == 0) s4[threadIdx.x >> 6] = v;
    __syncthreads();
    if (threadIdx.x == 0) {
        float t = (s4[0] + s4[1] + s4[2] + s4[3]) * (1.0f / (float)NROW);
        atomicAdd(out, t);
    }
}

extern "C" void kernel_launch(void* const* d_in, const int* in_sizes, int n_in,
                              void* d_out, int out_size, void* d_ws, size_t ws_size,
                              hipStream_t stream) {
    const float* h1 = (const float*)d_in[0];
    const float* h2 = (const float*)d_in[1];
    float* out = (float*)d_out;

    char* ws = (char*)d_ws;
    unsigned char* z1b = (unsigned char*)ws;                             // 2 MB
    unsigned char* z2b = (unsigned char*)(ws + (size_t)NROW * DDIM);     // 2 MB
    float* sums = (float*)(ws + (size_t)2 * NROW * DDIM);
    float* rs1  = sums;
    float* rs2  = sums + NROW;
    float* rbr  = sums + 2 * NROW;
    float* rbc  = sums + 3 * NROW;
    float* diag = sums + 4 * NROW;

    normalize_kernel<<<NROW / 4, 256, 0, stream>>>(h1, h2, z1b, z2b, diag,
                                                   rs1, rs2, rbr, rbc, out);

    expsum_kernel<<<NT_TOTAL, 512, 0, stream>>>(z1b, z2b, rs1, rs2, rbr, rbc);

    finalize_kernel<<<NROW / 256, 256, 0, stream>>>(rs1, rs2, rbr, rbc, diag, out);
}